// Round 6
// baseline (975.762 us; speedup 1.0000x reference)
//
#include <hip/hip_runtime.h>
#include <hip/hip_bf16.h>

#define NB 32    // batch
#define CC 64    // channels
#define VV 500   // nodes
#define LL 64    // time length
#define EE 10    // embedding dim
#define CO 64    // out channels
#define DIL 2    // dilation / shift step
#define VP 512   // padded V for MFMA (k and m padded)
#define SL (VV * LL)   // 32000 flattened (v,l)

typedef unsigned short u16;
typedef unsigned int   u32;
typedef __attribute__((ext_vector_type(8))) short bf16x8;
typedef __attribute__((ext_vector_type(4))) float f32x4;

__device__ __forceinline__ float bf2f(u16 u) {
    union { u32 i; float f; } c; c.i = ((u32)u) << 16; return c.f;
}
__device__ __forceinline__ u16 f2bf(float f) {
    union { float f; u32 i; } c; c.f = f;
    u32 x = c.i;
    u32 r = (x + 0x7fffu + ((x >> 16) & 1u)) >> 16; // RNE
    return (u16)r;
}

// ---------------------------------------------------------------------------
// K0: embedding affine update + mlp_w -> bf16 conversion
// ---------------------------------------------------------------------------
__global__ void emb_kernel(const float* __restrict__ nv1, const float* __restrict__ nv2,
                           const float* __restrict__ et_w, const float* __restrict__ et_b,
                           const float* __restrict__ mlp_w,
                           float* __restrict__ nv1t, float* __restrict__ nv2t,
                           u16* __restrict__ wb) {
    int idx = blockIdx.x * blockDim.x + threadIdx.x;
    if (idx < VV * EE) {
        int v = idx / EE, e = idx - v * EE;
        float s = et_b[e];
        #pragma unroll
        for (int f = 0; f < EE; f++) s += nv1[v * EE + f] * et_w[f * EE + e];
        nv1t[idx] = s;
    } else if (idx < 2 * VV * EE) {
        int k = idx - VV * EE;
        int e = k / VV, v = k - e * VV;
        float s = et_b[e];
        #pragma unroll
        for (int f = 0; f < EE; f++) s += nv2[f * VV + v] * et_w[f * EE + e];
        nv2t[k] = s;
    } else if (idx < 2 * VV * EE + CO * 3 * CC) {
        int k = idx - 2 * VV * EE;
        wb[k] = f2bf(mlp_w[k]);
    }
}

// ---------------------------------------------------------------------------
// K1: adjacency, bf16, zero-padded to [VP][VP], stored transposed.
// ---------------------------------------------------------------------------
__global__ __launch_bounds__(64) void adj_kernel(const float* __restrict__ p1,
                                                 const float* __restrict__ p2,
                                                 u16* __restrict__ Atb) {
    const int v = blockIdx.x;     // 0..VP-1
    const int lane = threadIdx.x;
    if (v >= VV) {
        #pragma unroll
        for (int j = 0; j < 8; j++) Atb[(size_t)(lane + 64 * j) * VP + v] = 0;
        return;
    }
    float e1[EE];
    #pragma unroll
    for (int e = 0; e < EE; e++) e1[e] = p1[v * EE + e];

    float r[8];
    float m = -1e30f;
    #pragma unroll
    for (int j = 0; j < 8; j++) {
        int w = lane + 64 * j;
        if (w < VV) {
            float s = 0.f;
            #pragma unroll
            for (int e = 0; e < EE; e++) s += e1[e] * p2[e * VV + w];
            r[j] = fmaxf(s, 0.f);
            m = fmaxf(m, r[j]);
        } else {
            r[j] = -1e30f;
        }
    }
    #pragma unroll
    for (int off = 32; off > 0; off >>= 1) m = fmaxf(m, __shfl_xor(m, off));

    float p[8];
    float sum = 0.f;
    #pragma unroll
    for (int j = 0; j < 8; j++) {
        int w = lane + 64 * j;
        if (w < VV) { p[j] = expf(r[j] - m); sum += p[j]; }
    }
    #pragma unroll
    for (int off = 32; off > 0; off >>= 1) sum += __shfl_xor(sum, off);
    float inv = 1.f / sum;
    #pragma unroll
    for (int j = 0; j < 8; j++) {
        int w = lane + 64 * j;
        Atb[(size_t)w * VP + v] = (w < VV) ? f2bf(p[j] * inv) : (u16)0;
    }
}

// ---------------------------------------------------------------------------
// K2: hop via MFMA, PERSISTENT + register-pipelined (T14 async-STAGE split).
// Grid = 256 blocks (1/CU), each owns 8 consecutive planes.
// Per plane: regs hold plane t (issued last iter) -> convert+LDS write ->
// barrier -> ISSUE plane t+1 loads (overlap compute) -> MFMA K-loop + store
// (epilogue shift) -> barrier. LDS single buffer 64 KB.
// ---------------------------------------------------------------------------
template<int SHIFT, int IN_BF16>
__global__ __launch_bounds__(512, 2) void hop_mfma(const void* __restrict__ xin_,
                                                   const u16* __restrict__ Atb,
                                                   u16* __restrict__ xout) {
    __shared__ u16 Xt[LL * VP];   // [l][v] swizzled, 64 KB
    const int tid = threadIdx.x;
    const int lane = tid & 63;
    const int wv = tid >> 6;

    // staging geometry
    const int lquad = lane & 15;
    const int vsub = lane >> 4;     // 0..3
    const int l0 = 4 * lquad;

    // compute geometry (constant across planes)
    const int wr = wv * 64;
    const int r15 = lane & 15;
    const int kg = lane >> 4;
    const u16* arow[4];
    #pragma unroll
    for (int rt = 0; rt < 4; rt++)
        arow[rt] = Atb + (size_t)(wr + rt * 16 + r15) * VP + kg * 8;
    int lrow[4], lswz[4];
    #pragma unroll
    for (int ct = 0; ct < 4; ct++) {
        const int l = ct * 16 + r15;
        lrow[ct] = l * (VP * 2);
        lswz[ct] = (l & 7) << 4;
    }

    // register staging buffers (only one set lives per template instance)
    float4 fa[8], fb[8];
    uint2  ua[8], ub[8];

    const int nc0 = blockIdx.x * 8;

    // ---- prologue: issue loads for plane 0 ----
    {
        const size_t base = (size_t)nc0 * (VV * LL);
        #pragma unroll
        for (int i = 0; i < 8; ++i) {
            const int v0 = 2 * (wv * 32 + i * 4 + vsub);
            if (v0 < VV) {
                if (IN_BF16) {
                    const u16* xa = (const u16*)xin_ + base + v0 * LL + l0;
                    ua[i] = *(const uint2*)xa;
                    ub[i] = *(const uint2*)(xa + LL);
                } else {
                    const float* xa = (const float*)xin_ + base + v0 * LL + l0;
                    fa[i] = *(const float4*)xa;
                    fb[i] = *(const float4*)(xa + LL);
                }
            }
        }
    }

    #pragma unroll 1
    for (int t = 0; t < 8; ++t) {
        const int nc = nc0 + t;
        const size_t base = (size_t)nc * (VV * LL);

        // ---- convert regs -> LDS (waits on loads) ----
        {
            char* ldsb = (char*)Xt;
            #pragma unroll
            for (int i = 0; i < 8; ++i) {
                const int vp = wv * 32 + i * 4 + vsub;
                const int v0 = 2 * vp;
                u32 pk0, pk1, pk2, pk3;
                if (v0 < VV) {
                    if (IN_BF16) {
                        pk0 = (ua[i].x & 0xffffu) | (ub[i].x << 16);
                        pk1 = (ua[i].x >> 16) | (ub[i].x & 0xffff0000u);
                        pk2 = (ua[i].y & 0xffffu) | (ub[i].y << 16);
                        pk3 = (ua[i].y >> 16) | (ub[i].y & 0xffff0000u);
                    } else {
                        pk0 = (u32)f2bf(fa[i].x) | ((u32)f2bf(fb[i].x) << 16);
                        pk1 = (u32)f2bf(fa[i].y) | ((u32)f2bf(fb[i].y) << 16);
                        pk2 = (u32)f2bf(fa[i].z) | ((u32)f2bf(fb[i].z) << 16);
                        pk3 = (u32)f2bf(fa[i].w) | ((u32)f2bf(fb[i].w) << 16);
                    }
                } else {
                    pk0 = pk1 = pk2 = pk3 = 0;
                }
                const int vb = 4 * vp;
                int l = l0;
                *(u32*)(ldsb + l * (VP * 2) + (vb ^ ((l & 7) << 4))) = pk0; l++;
                *(u32*)(ldsb + l * (VP * 2) + (vb ^ ((l & 7) << 4))) = pk1; l++;
                *(u32*)(ldsb + l * (VP * 2) + (vb ^ ((l & 7) << 4))) = pk2; l++;
                *(u32*)(ldsb + l * (VP * 2) + (vb ^ ((l & 7) << 4))) = pk3;
            }
        }
        __syncthreads();

        // ---- issue next plane's loads (overlap with compute below) ----
        if (t + 1 < 8) {
            const size_t nbase = (size_t)(nc + 1) * (VV * LL);
            #pragma unroll
            for (int i = 0; i < 8; ++i) {
                const int v0 = 2 * (wv * 32 + i * 4 + vsub);
                if (v0 < VV) {
                    if (IN_BF16) {
                        const u16* xa = (const u16*)xin_ + nbase + v0 * LL + l0;
                        ua[i] = *(const uint2*)xa;
                        ub[i] = *(const uint2*)(xa + LL);
                    } else {
                        const float* xa = (const float*)xin_ + nbase + v0 * LL + l0;
                        fa[i] = *(const float4*)xa;
                        fb[i] = *(const float4*)(xa + LL);
                    }
                }
            }
        }

        // ---- MFMA main loop ----
        f32x4 acc[4][4];
        #pragma unroll
        for (int rt = 0; rt < 4; rt++)
            #pragma unroll
            for (int ct = 0; ct < 4; ct++)
                acc[rt][ct] = (f32x4){0.f, 0.f, 0.f, 0.f};

        const char* ldsb = (const char*)Xt;
        #pragma unroll
        for (int kb = 0; kb < VP; kb += 32) {
            bf16x8 a[4], b[4];
            #pragma unroll
            for (int rt = 0; rt < 4; rt++)
                a[rt] = *(const bf16x8*)(arow[rt] + kb);
            #pragma unroll
            for (int ct = 0; ct < 4; ct++)
                b[ct] = *(const bf16x8*)(ldsb + lrow[ct] + ((kb * 2 + kg * 16) ^ lswz[ct]));
            #pragma unroll
            for (int rt = 0; rt < 4; rt++)
                #pragma unroll
                for (int ct = 0; ct < 4; ct++)
                    acc[rt][ct] = __builtin_amdgcn_mfma_f32_16x16x32_bf16(a[rt], b[ct], acc[rt][ct], 0, 0, 0);
        }

        // ---- store with epilogue shift ----
        u16* xo = xout + base;
        #pragma unroll
        for (int rt = 0; rt < 4; rt++) {
            #pragma unroll
            for (int ct = 0; ct < 4; ct++) {
                const int col = ct * 16 + r15;
                const int wbase = wr + rt * 16 + kg * 4;
                f32x4 c = acc[rt][ct];
                #pragma unroll
                for (int r = 0; r < 4; r++) {
                    int w = wbase + r;
                    if (w < VV) {
                        if (SHIFT > 0 && col < SHIFT) xo[w * LL + col] = 0;
                        if (col + SHIFT < LL) xo[w * LL + col + SHIFT] = f2bf(c[r]);
                    }
                }
            }
        }
        __syncthreads();   // protect LDS from next plane's convert
    }
}

// ---------------------------------------------------------------------------
// K3: MLP via MFMA.  Staging v2: wide loads.
// Lane (squad=tid>>3 0..31, pgroup=tid&7): item i in 0..11: c-pair P=i*8+pgroup,
// loads planes 2P,2P+1 at s-quad 4*squad via float4 (i<4, fp32) / uint2 (bf16),
// packs in-lane, 4 swizzled u32 LDS writes. 24 wide VMEM per thread (was 96 scalar).
// ---------------------------------------------------------------------------
__global__ __launch_bounds__(256, 3) void mlp_mfma(const float* __restrict__ x,
                                                   const u16* __restrict__ x1,
                                                   const u16* __restrict__ x2,
                                                   const u16* __restrict__ wb,
                                                   const float* __restrict__ b,
                                                   float* __restrict__ out) {
    __shared__ u16 Ht[128 * 192];   // 49152 B
    const int bid = blockIdx.x;
    const int n = bid / (SL / 128);
    const int st = bid - n * (SL / 128);
    const int s0 = st * 128;
    const int tid = threadIdx.x;

    const int lane = tid & 63;
    const int wv = tid >> 6;
    const int obase = (wv & 1) * 32;
    const int sbase = (wv >> 1) * 64;
    const int r15 = lane & 15;
    const int kg = lane >> 4;

    bf16x8 afrag[2][6];
    #pragma unroll
    for (int rt = 0; rt < 2; rt++)
        #pragma unroll
        for (int ks = 0; ks < 6; ks++)
            afrag[rt][ks] = *(const bf16x8*)(wb + (obase + rt * 16 + r15) * (3 * CC) + ks * 32 + kg * 8);

    // ---- staging: wide loads + swizzled writes ----
    {
        char* ldsb = (char*)Ht;
        const int squad = tid >> 3;      // 0..31
        const int pgroup = tid & 7;      // 0..7
        const int sq0 = 4 * squad;       // 0..124
        #pragma unroll
        for (int i = 0; i < 12; ++i) {
            const int P = i * 8 + pgroup;   // 0..95
            const int c = 2 * P;
            u32 pk0, pk1, pk2, pk3;
            if (i < 4) {    // c < 64: fp32 source
                const float* fsrc = x + ((size_t)n * CC + c) * SL + s0 + sq0;
                float4 va = *(const float4*)fsrc;
                float4 vb = *(const float4*)(fsrc + SL);
                pk0 = (u32)f2bf(va.x) | ((u32)f2bf(vb.x) << 16);
                pk1 = (u32)f2bf(va.y) | ((u32)f2bf(vb.y) << 16);
                pk2 = (u32)f2bf(va.z) | ((u32)f2bf(vb.z) << 16);
                pk3 = (u32)f2bf(va.w) | ((u32)f2bf(vb.w) << 16);
            } else {        // bf16 source (x1 for i<8, else x2)
                const u16* bsrc = (i < 8)
                    ? x1 + ((size_t)n * CC + (c - CC)) * SL + s0 + sq0
                    : x2 + ((size_t)n * CC + (c - 2 * CC)) * SL + s0 + sq0;
                uint2 va = *(const uint2*)bsrc;
                uint2 vb = *(const uint2*)(bsrc + SL);
                pk0 = (va.x & 0xffffu) | (vb.x << 16);
                pk1 = (va.x >> 16) | (vb.x & 0xffff0000u);
                pk2 = (va.y & 0xffffu) | (vb.y << 16);
                pk3 = (va.y >> 16) | (vb.y & 0xffff0000u);
            }
            int s = sq0;
            *(u32*)(ldsb + s * 384 + ((4 * P) ^ ((s & 7) << 4))) = pk0; s++;
            *(u32*)(ldsb + s * 384 + ((4 * P) ^ ((s & 7) << 4))) = pk1; s++;
            *(u32*)(ldsb + s * 384 + ((4 * P) ^ ((s & 7) << 4))) = pk2; s++;
            *(u32*)(ldsb + s * 384 + ((4 * P) ^ ((s & 7) << 4))) = pk3;
        }
    }
    __syncthreads();

    f32x4 acc[2][4];
    #pragma unroll
    for (int rt = 0; rt < 2; rt++)
        #pragma unroll
        for (int ct = 0; ct < 4; ct++)
            acc[rt][ct] = (f32x4){0.f, 0.f, 0.f, 0.f};

    const char* ldsb = (const char*)Ht;
    #pragma unroll
    for (int ks = 0; ks < 6; ks++) {
        bf16x8 bfr[4];
        #pragma unroll
        for (int ct = 0; ct < 4; ct++) {
            const int s = sbase + ct * 16 + r15;
            bfr[ct] = *(const bf16x8*)(ldsb + s * 384 + ((ks * 64 + kg * 16) ^ ((s & 7) << 4)));
        }
        #pragma unroll
        for (int rt = 0; rt < 2; rt++)
            #pragma unroll
            for (int ct = 0; ct < 4; ct++)
                acc[rt][ct] = __builtin_amdgcn_mfma_f32_16x16x32_bf16(afrag[rt][ks], bfr[ct], acc[rt][ct], 0, 0, 0);
    }

    #pragma unroll
    for (int rt = 0; rt < 2; rt++) {
        #pragma unroll
        for (int r = 0; r < 4; r++) {
            const int o = obase + rt * 16 + kg * 4 + r;
            const float bias = b[o];
            float* orow = out + ((size_t)n * CO + o) * SL + s0 + sbase;
            #pragma unroll
            for (int ct = 0; ct < 4; ct++)
                orow[ct * 16 + r15] = acc[rt][ct][r] + bias;
        }
    }
}

// ---------------------------------------------------------------------------
extern "C" void kernel_launch(void* const* d_in, const int* in_sizes, int n_in,
                              void* d_out, int out_size, void* d_ws, size_t ws_size,
                              hipStream_t stream) {
    const float* x     = (const float*)d_in[0];
    const float* nv1   = (const float*)d_in[1];
    const float* nv2   = (const float*)d_in[2];
    const float* et_w  = (const float*)d_in[3];
    const float* et_b  = (const float*)d_in[4];
    const float* mlp_w = (const float*)d_in[5];
    const float* mlp_b = (const float*)d_in[6];
    float* out = (float*)d_out;

    char* wsb = (char*)d_ws;
    size_t off = 0;
    auto alloc = [&](size_t bytes) {
        size_t o = off;
        off += (bytes + 255) & ~(size_t)255;
        return o;
    };
    u16*   Atb0 = (u16*)(wsb + alloc((size_t)VP * VP * 2));
    u16*   Atb1 = (u16*)(wsb + alloc((size_t)VP * VP * 2));
    float* nv1t = (float*)(wsb + alloc((size_t)VV * EE * 4));
    float* nv2t = (float*)(wsb + alloc((size_t)EE * VV * 4));
    u16*   wb   = (u16*)(wsb + alloc((size_t)CO * 3 * CC * 2));
    u16*   x1   = (u16*)(wsb + alloc((size_t)NB * CC * VV * LL * 2));
    u16*   x2   = (u16*)(wsb + alloc((size_t)NB * CC * VV * LL * 2));
    (void)in_sizes; (void)n_in; (void)out_size; (void)ws_size;

    const int embN = 2 * VV * EE + CO * 3 * CC;
    emb_kernel<<<(embN + 255) / 256, 256, 0, stream>>>(nv1, nv2, et_w, et_b, mlp_w, nv1t, nv2t, wb);
    adj_kernel<<<VP, 64, 0, stream>>>(nv1, nv2, Atb0);
    adj_kernel<<<VP, 64, 0, stream>>>(nv1t, nv2t, Atb1);
    hop_mfma<0, 0><<<NB * CC / 8, 512, 0, stream>>>((const void*)x, Atb0, x1);
    hop_mfma<DIL, 1><<<NB * CC / 8, 512, 0, stream>>>((const void*)x1, Atb1, x2);
    mlp_mfma<<<NB * (SL / 128), 256, 0, stream>>>(x, x1, x2, wb, mlp_b, out);
}

// Round 7
// 554.715 us; speedup vs baseline: 1.7590x; 1.7590x over previous
//
#include <hip/hip_runtime.h>
#include <hip/hip_bf16.h>

#define NB 32    // batch
#define CC 64    // channels
#define VV 500   // nodes
#define LL 64    // time length
#define EE 10    // embedding dim
#define CO 64    // out channels
#define DIL 2    // dilation / shift step
#define VP 512   // padded V for MFMA (k and m padded)
#define SL (VV * LL)   // 32000 flattened (v,l)

typedef unsigned short u16;
typedef unsigned int   u32;
typedef __attribute__((ext_vector_type(8))) short bf16x8;
typedef __attribute__((ext_vector_type(4))) float f32x4;

__device__ __forceinline__ float bf2f(u16 u) {
    union { u32 i; float f; } c; c.i = ((u32)u) << 16; return c.f;
}
__device__ __forceinline__ u16 f2bf(float f) {
    union { float f; u32 i; } c; c.f = f;
    u32 x = c.i;
    u32 r = (x + 0x7fffu + ((x >> 16) & 1u)) >> 16; // RNE
    return (u16)r;
}

// ---------------------------------------------------------------------------
// K0: embedding affine update + mlp_w -> bf16 conversion
// ---------------------------------------------------------------------------
__global__ void emb_kernel(const float* __restrict__ nv1, const float* __restrict__ nv2,
                           const float* __restrict__ et_w, const float* __restrict__ et_b,
                           const float* __restrict__ mlp_w,
                           float* __restrict__ nv1t, float* __restrict__ nv2t,
                           u16* __restrict__ wb) {
    int idx = blockIdx.x * blockDim.x + threadIdx.x;
    if (idx < VV * EE) {
        int v = idx / EE, e = idx - v * EE;
        float s = et_b[e];
        #pragma unroll
        for (int f = 0; f < EE; f++) s += nv1[v * EE + f] * et_w[f * EE + e];
        nv1t[idx] = s;
    } else if (idx < 2 * VV * EE) {
        int k = idx - VV * EE;
        int e = k / VV, v = k - e * VV;
        float s = et_b[e];
        #pragma unroll
        for (int f = 0; f < EE; f++) s += nv2[f * VV + v] * et_w[f * EE + e];
        nv2t[k] = s;
    } else if (idx < 2 * VV * EE + CO * 3 * CC) {
        int k = idx - 2 * VV * EE;
        wb[k] = f2bf(mlp_w[k]);
    }
}

// ---------------------------------------------------------------------------
// K1: adjacency, bf16, zero-padded to [VP][VP], stored transposed.
// ---------------------------------------------------------------------------
__global__ __launch_bounds__(64) void adj_kernel(const float* __restrict__ p1,
                                                 const float* __restrict__ p2,
                                                 u16* __restrict__ Atb) {
    const int v = blockIdx.x;     // 0..VP-1
    const int lane = threadIdx.x;
    if (v >= VV) {
        #pragma unroll
        for (int j = 0; j < 8; j++) Atb[(size_t)(lane + 64 * j) * VP + v] = 0;
        return;
    }
    float e1[EE];
    #pragma unroll
    for (int e = 0; e < EE; e++) e1[e] = p1[v * EE + e];

    float r[8];
    float m = -1e30f;
    #pragma unroll
    for (int j = 0; j < 8; j++) {
        int w = lane + 64 * j;
        if (w < VV) {
            float s = 0.f;
            #pragma unroll
            for (int e = 0; e < EE; e++) s += e1[e] * p2[e * VV + w];
            r[j] = fmaxf(s, 0.f);
            m = fmaxf(m, r[j]);
        } else {
            r[j] = -1e30f;
        }
    }
    #pragma unroll
    for (int off = 32; off > 0; off >>= 1) m = fmaxf(m, __shfl_xor(m, off));

    float p[8];
    float sum = 0.f;
    #pragma unroll
    for (int j = 0; j < 8; j++) {
        int w = lane + 64 * j;
        if (w < VV) { p[j] = expf(r[j] - m); sum += p[j]; }
    }
    #pragma unroll
    for (int off = 32; off > 0; off >>= 1) sum += __shfl_xor(sum, off);
    float inv = 1.f / sum;
    #pragma unroll
    for (int j = 0; j < 8; j++) {
        int w = lane + 64 * j;
        Atb[(size_t)w * VP + v] = (w < VV) ? f2bf(p[j] * inv) : (u16)0;
    }
}

// ---------------------------------------------------------------------------
// K2: hop via MFMA (R4 structure: grid = NB*CC, one plane per block).
//   D[w][l] = sum_v Atb[w][v] * X[v][l]  (UNSHIFTED);
//   epilogue writes out[w][l] = D[w][l-SHIFT] (0 for l<SHIFT).
// Staging v3: wave wv stages rows v in [wv*64, +64) with float4/uint2 wide
// loads (16 lanes x 16B contiguous per row), in-lane pair pack, swizzled
// u32 LDS writes. K-loop: depth-1 software prefetch of A-fragments (L2).
// ---------------------------------------------------------------------------
template<int SHIFT, int IN_BF16>
__global__ __launch_bounds__(512, 4) void hop_mfma(const void* __restrict__ xin_,
                                                   const u16* __restrict__ Atb,
                                                   u16* __restrict__ xout) {
    __shared__ u16 Xt[LL * VP];   // [l][v] swizzled, 64 KB
    const int nc = blockIdx.x;
    const int tid = threadIdx.x;
    const size_t base = (size_t)nc * (VV * LL);
    const int lane = tid & 63;
    const int wv = tid >> 6;

    // ---- stage (transpose + bf16, no shift) ----
    {
        char* ldsb = (char*)Xt;
        const int lquad = lane & 15;
        const int vsub = lane >> 4;     // 0..3
        const int l0 = 4 * lquad;
        #pragma unroll
        for (int i = 0; i < 8; ++i) {
            const int vp = wv * 32 + i * 4 + vsub;  // v-pair 0..255
            const int v0 = 2 * vp;
            u32 pk0, pk1, pk2, pk3;
            if (v0 < VV) {   // VV even => v0 < VV implies v0+1 < VV
                if (IN_BF16) {
                    const u16* xa = (const u16*)xin_ + base + v0 * LL + l0;
                    uint2 ua = *(const uint2*)xa;
                    uint2 ub = *(const uint2*)(xa + LL);
                    pk0 = (ua.x & 0xffffu) | (ub.x << 16);
                    pk1 = (ua.x >> 16) | (ub.x & 0xffff0000u);
                    pk2 = (ua.y & 0xffffu) | (ub.y << 16);
                    pk3 = (ua.y >> 16) | (ub.y & 0xffff0000u);
                } else {
                    const float* xa = (const float*)xin_ + base + v0 * LL + l0;
                    float4 fa = *(const float4*)xa;
                    float4 fb = *(const float4*)(xa + LL);
                    pk0 = (u32)f2bf(fa.x) | ((u32)f2bf(fb.x) << 16);
                    pk1 = (u32)f2bf(fa.y) | ((u32)f2bf(fb.y) << 16);
                    pk2 = (u32)f2bf(fa.z) | ((u32)f2bf(fb.z) << 16);
                    pk3 = (u32)f2bf(fa.w) | ((u32)f2bf(fb.w) << 16);
                }
            } else {
                pk0 = pk1 = pk2 = pk3 = 0;
            }
            const int vb = 4 * vp;
            int l = l0;
            *(u32*)(ldsb + l * (VP * 2) + (vb ^ ((l & 7) << 4))) = pk0; l++;
            *(u32*)(ldsb + l * (VP * 2) + (vb ^ ((l & 7) << 4))) = pk1; l++;
            *(u32*)(ldsb + l * (VP * 2) + (vb ^ ((l & 7) << 4))) = pk2; l++;
            *(u32*)(ldsb + l * (VP * 2) + (vb ^ ((l & 7) << 4))) = pk3;
        }
    }
    __syncthreads();

    // ---- MFMA main loop (A prefetch depth 1) ----
    const int wr = wv * 64;
    const int r15 = lane & 15;
    const int kg = lane >> 4;

    f32x4 acc[4][4];
    #pragma unroll
    for (int rt = 0; rt < 4; rt++)
        #pragma unroll
        for (int ct = 0; ct < 4; ct++)
            acc[rt][ct] = (f32x4){0.f, 0.f, 0.f, 0.f};

    const char* ldsb = (const char*)Xt;
    const u16* arow[4];
    #pragma unroll
    for (int rt = 0; rt < 4; rt++)
        arow[rt] = Atb + (size_t)(wr + rt * 16 + r15) * VP + kg * 8;
    int lrow[4], lswz[4];
    #pragma unroll
    for (int ct = 0; ct < 4; ct++) {
        const int l = ct * 16 + r15;
        lrow[ct] = l * (VP * 2);
        lswz[ct] = (l & 7) << 4;
    }

    bf16x8 a[4], an[4];
    #pragma unroll
    for (int rt = 0; rt < 4; rt++)
        a[rt] = *(const bf16x8*)(arow[rt]);

    #pragma unroll
    for (int kb = 0; kb < VP; kb += 32) {
        bf16x8 b[4];
        #pragma unroll
        for (int ct = 0; ct < 4; ct++)
            b[ct] = *(const bf16x8*)(ldsb + lrow[ct] + ((kb * 2 + kg * 16) ^ lswz[ct]));
        if (kb + 32 < VP) {
            #pragma unroll
            for (int rt = 0; rt < 4; rt++)
                an[rt] = *(const bf16x8*)(arow[rt] + kb + 32);
        }
        #pragma unroll
        for (int rt = 0; rt < 4; rt++)
            #pragma unroll
            for (int ct = 0; ct < 4; ct++)
                acc[rt][ct] = __builtin_amdgcn_mfma_f32_16x16x32_bf16(a[rt], b[ct], acc[rt][ct], 0, 0, 0);
        #pragma unroll
        for (int rt = 0; rt < 4; rt++)
            a[rt] = an[rt];
    }

    // ---- store with epilogue shift: out[w][col+SHIFT] = D[w][col] ----
    u16* xo = xout + base;
    #pragma unroll
    for (int rt = 0; rt < 4; rt++) {
        #pragma unroll
        for (int ct = 0; ct < 4; ct++) {
            const int col = ct * 16 + r15;
            const int wbase = wr + rt * 16 + kg * 4;
            f32x4 c = acc[rt][ct];
            #pragma unroll
            for (int r = 0; r < 4; r++) {
                int w = wbase + r;
                if (w < VV) {
                    if (SHIFT > 0 && col < SHIFT) xo[w * LL + col] = 0;
                    if (col + SHIFT < LL) xo[w * LL + col + SHIFT] = f2bf(c[r]);
                }
            }
        }
    }
}

// ---------------------------------------------------------------------------
// K3: MLP via MFMA.  Staging: wide loads (R5 version).
// Lane (squad=tid>>3 0..31, pgroup=tid&7): item i in 0..11: c-pair P=i*8+pgroup,
// loads planes 2P,2P+1 at s-quad 4*squad via float4 (i<4, fp32) / uint2 (bf16),
// packs in-lane, 4 swizzled u32 LDS writes. 24 wide VMEM per thread.
// ---------------------------------------------------------------------------
__global__ __launch_bounds__(256, 3) void mlp_mfma(const float* __restrict__ x,
                                                   const u16* __restrict__ x1,
                                                   const u16* __restrict__ x2,
                                                   const u16* __restrict__ wb,
                                                   const float* __restrict__ b,
                                                   float* __restrict__ out) {
    __shared__ u16 Ht[128 * 192];   // 49152 B
    const int bid = blockIdx.x;
    const int n = bid / (SL / 128);
    const int st = bid - n * (SL / 128);
    const int s0 = st * 128;
    const int tid = threadIdx.x;

    const int lane = tid & 63;
    const int wv = tid >> 6;
    const int obase = (wv & 1) * 32;
    const int sbase = (wv >> 1) * 64;
    const int r15 = lane & 15;
    const int kg = lane >> 4;

    bf16x8 afrag[2][6];
    #pragma unroll
    for (int rt = 0; rt < 2; rt++)
        #pragma unroll
        for (int ks = 0; ks < 6; ks++)
            afrag[rt][ks] = *(const bf16x8*)(wb + (obase + rt * 16 + r15) * (3 * CC) + ks * 32 + kg * 8);

    // ---- staging: wide loads + swizzled writes ----
    {
        char* ldsb = (char*)Ht;
        const int squad = tid >> 3;      // 0..31
        const int pgroup = tid & 7;      // 0..7
        const int sq0 = 4 * squad;       // 0..124
        #pragma unroll
        for (int i = 0; i < 12; ++i) {
            const int P = i * 8 + pgroup;   // 0..95
            const int c = 2 * P;
            u32 pk0, pk1, pk2, pk3;
            if (i < 4) {    // c < 64: fp32 source
                const float* fsrc = x + ((size_t)n * CC + c) * SL + s0 + sq0;
                float4 va = *(const float4*)fsrc;
                float4 vb = *(const float4*)(fsrc + SL);
                pk0 = (u32)f2bf(va.x) | ((u32)f2bf(vb.x) << 16);
                pk1 = (u32)f2bf(va.y) | ((u32)f2bf(vb.y) << 16);
                pk2 = (u32)f2bf(va.z) | ((u32)f2bf(vb.z) << 16);
                pk3 = (u32)f2bf(va.w) | ((u32)f2bf(vb.w) << 16);
            } else {        // bf16 source (x1 for i<8, else x2)
                const u16* bsrc = (i < 8)
                    ? x1 + ((size_t)n * CC + (c - CC)) * SL + s0 + sq0
                    : x2 + ((size_t)n * CC + (c - 2 * CC)) * SL + s0 + sq0;
                uint2 va = *(const uint2*)bsrc;
                uint2 vb = *(const uint2*)(bsrc + SL);
                pk0 = (va.x & 0xffffu) | (vb.x << 16);
                pk1 = (va.x >> 16) | (vb.x & 0xffff0000u);
                pk2 = (va.y & 0xffffu) | (vb.y << 16);
                pk3 = (va.y >> 16) | (vb.y & 0xffff0000u);
            }
            int s = sq0;
            *(u32*)(ldsb + s * 384 + ((4 * P) ^ ((s & 7) << 4))) = pk0; s++;
            *(u32*)(ldsb + s * 384 + ((4 * P) ^ ((s & 7) << 4))) = pk1; s++;
            *(u32*)(ldsb + s * 384 + ((4 * P) ^ ((s & 7) << 4))) = pk2; s++;
            *(u32*)(ldsb + s * 384 + ((4 * P) ^ ((s & 7) << 4))) = pk3;
        }
    }
    __syncthreads();

    f32x4 acc[2][4];
    #pragma unroll
    for (int rt = 0; rt < 2; rt++)
        #pragma unroll
        for (int ct = 0; ct < 4; ct++)
            acc[rt][ct] = (f32x4){0.f, 0.f, 0.f, 0.f};

    const char* ldsb = (const char*)Ht;
    #pragma unroll
    for (int ks = 0; ks < 6; ks++) {
        bf16x8 bfr[4];
        #pragma unroll
        for (int ct = 0; ct < 4; ct++) {
            const int s = sbase + ct * 16 + r15;
            bfr[ct] = *(const bf16x8*)(ldsb + s * 384 + ((ks * 64 + kg * 16) ^ ((s & 7) << 4)));
        }
        #pragma unroll
        for (int rt = 0; rt < 2; rt++)
            #pragma unroll
            for (int ct = 0; ct < 4; ct++)
                acc[rt][ct] = __builtin_amdgcn_mfma_f32_16x16x32_bf16(afrag[rt][ks], bfr[ct], acc[rt][ct], 0, 0, 0);
    }

    #pragma unroll
    for (int rt = 0; rt < 2; rt++) {
        #pragma unroll
        for (int r = 0; r < 4; r++) {
            const int o = obase + rt * 16 + kg * 4 + r;
            const float bias = b[o];
            float* orow = out + ((size_t)n * CO + o) * SL + s0 + sbase;
            #pragma unroll
            for (int ct = 0; ct < 4; ct++)
                orow[ct * 16 + r15] = acc[rt][ct][r] + bias;
        }
    }
}

// ---------------------------------------------------------------------------
extern "C" void kernel_launch(void* const* d_in, const int* in_sizes, int n_in,
                              void* d_out, int out_size, void* d_ws, size_t ws_size,
                              hipStream_t stream) {
    const float* x     = (const float*)d_in[0];
    const float* nv1   = (const float*)d_in[1];
    const float* nv2   = (const float*)d_in[2];
    const float* et_w  = (const float*)d_in[3];
    const float* et_b  = (const float*)d_in[4];
    const float* mlp_w = (const float*)d_in[5];
    const float* mlp_b = (const float*)d_in[6];
    float* out = (float*)d_out;

    char* wsb = (char*)d_ws;
    size_t off = 0;
    auto alloc = [&](size_t bytes) {
        size_t o = off;
        off += (bytes + 255) & ~(size_t)255;
        return o;
    };
    u16*   Atb0 = (u16*)(wsb + alloc((size_t)VP * VP * 2));
    u16*   Atb1 = (u16*)(wsb + alloc((size_t)VP * VP * 2));
    float* nv1t = (float*)(wsb + alloc((size_t)VV * EE * 4));
    float* nv2t = (float*)(wsb + alloc((size_t)EE * VV * 4));
    u16*   wb   = (u16*)(wsb + alloc((size_t)CO * 3 * CC * 2));
    u16*   x1   = (u16*)(wsb + alloc((size_t)NB * CC * VV * LL * 2));
    u16*   x2   = (u16*)(wsb + alloc((size_t)NB * CC * VV * LL * 2));
    (void)in_sizes; (void)n_in; (void)out_size; (void)ws_size;

    const int embN = 2 * VV * EE + CO * 3 * CC;
    emb_kernel<<<(embN + 255) / 256, 256, 0, stream>>>(nv1, nv2, et_w, et_b, mlp_w, nv1t, nv2t, wb);
    adj_kernel<<<VP, 64, 0, stream>>>(nv1, nv2, Atb0);
    adj_kernel<<<VP, 64, 0, stream>>>(nv1t, nv2t, Atb1);
    hop_mfma<0, 0><<<NB * CC, 512, 0, stream>>>((const void*)x, Atb0, x1);
    hop_mfma<DIL, 1><<<NB * CC, 512, 0, stream>>>((const void*)x1, Atb1, x2);
    mlp_mfma<<<NB * (SL / 128), 256, 0, stream>>>(x, x1, x2, wb, mlp_b, out);
}

// Round 8
// 552.872 us; speedup vs baseline: 1.7649x; 1.0033x over previous
//
#include <hip/hip_runtime.h>
#include <hip/hip_bf16.h>

#define NB 32    // batch
#define CC 64    // channels
#define VV 500   // nodes
#define LL 64    // time length
#define EE 10    // embedding dim
#define CO 64    // out channels
#define DIL 2    // dilation / shift step
#define VP 512   // padded V for MFMA (k and m padded)
#define SL (VV * LL)   // 32000 flattened (v,l)

typedef unsigned short u16;
typedef unsigned int   u32;
typedef __attribute__((ext_vector_type(8))) short bf16x8;
typedef __attribute__((ext_vector_type(4))) float f32x4;

__device__ __forceinline__ float bf2f(u16 u) {
    union { u32 i; float f; } c; c.i = ((u32)u) << 16; return c.f;
}
__device__ __forceinline__ u16 f2bf(float f) {
    union { float f; u32 i; } c; c.f = f;
    u32 x = c.i;
    u32 r = (x + 0x7fffu + ((x >> 16) & 1u)) >> 16; // RNE
    return (u16)r;
}

// ---------------------------------------------------------------------------
// K0: embedding affine update + mlp_w -> bf16 conversion
// ---------------------------------------------------------------------------
__global__ void emb_kernel(const float* __restrict__ nv1, const float* __restrict__ nv2,
                           const float* __restrict__ et_w, const float* __restrict__ et_b,
                           const float* __restrict__ mlp_w,
                           float* __restrict__ nv1t, float* __restrict__ nv2t,
                           u16* __restrict__ wb) {
    int idx = blockIdx.x * blockDim.x + threadIdx.x;
    if (idx < VV * EE) {
        int v = idx / EE, e = idx - v * EE;
        float s = et_b[e];
        #pragma unroll
        for (int f = 0; f < EE; f++) s += nv1[v * EE + f] * et_w[f * EE + e];
        nv1t[idx] = s;
    } else if (idx < 2 * VV * EE) {
        int k = idx - VV * EE;
        int e = k / VV, v = k - e * VV;
        float s = et_b[e];
        #pragma unroll
        for (int f = 0; f < EE; f++) s += nv2[f * VV + v] * et_w[f * EE + e];
        nv2t[k] = s;
    } else if (idx < 2 * VV * EE + CO * 3 * CC) {
        int k = idx - 2 * VV * EE;
        wb[k] = f2bf(mlp_w[k]);
    }
}

// ---------------------------------------------------------------------------
// K1: adjacency, bf16, zero-padded to [VP][VP], stored transposed.
// ---------------------------------------------------------------------------
__global__ __launch_bounds__(64) void adj_kernel(const float* __restrict__ p1,
                                                 const float* __restrict__ p2,
                                                 u16* __restrict__ Atb) {
    const int v = blockIdx.x;     // 0..VP-1
    const int lane = threadIdx.x;
    if (v >= VV) {
        #pragma unroll
        for (int j = 0; j < 8; j++) Atb[(size_t)(lane + 64 * j) * VP + v] = 0;
        return;
    }
    float e1[EE];
    #pragma unroll
    for (int e = 0; e < EE; e++) e1[e] = p1[v * EE + e];

    float r[8];
    float m = -1e30f;
    #pragma unroll
    for (int j = 0; j < 8; j++) {
        int w = lane + 64 * j;
        if (w < VV) {
            float s = 0.f;
            #pragma unroll
            for (int e = 0; e < EE; e++) s += e1[e] * p2[e * VV + w];
            r[j] = fmaxf(s, 0.f);
            m = fmaxf(m, r[j]);
        } else {
            r[j] = -1e30f;
        }
    }
    #pragma unroll
    for (int off = 32; off > 0; off >>= 1) m = fmaxf(m, __shfl_xor(m, off));

    float p[8];
    float sum = 0.f;
    #pragma unroll
    for (int j = 0; j < 8; j++) {
        int w = lane + 64 * j;
        if (w < VV) { p[j] = expf(r[j] - m); sum += p[j]; }
    }
    #pragma unroll
    for (int off = 32; off > 0; off >>= 1) sum += __shfl_xor(sum, off);
    float inv = 1.f / sum;
    #pragma unroll
    for (int j = 0; j < 8; j++) {
        int w = lane + 64 * j;
        Atb[(size_t)w * VP + v] = (w < VV) ? f2bf(p[j] * inv) : (u16)0;
    }
}

// ---------------------------------------------------------------------------
// K2: hop via MFMA (grid = NB*CC, one plane per block).
//   D[w][l] = sum_v Atb[w][v] * X[v][l]  (UNSHIFTED);
//   epilogue writes out[w][l] = D[w][l-SHIFT] (0 for l<SHIFT).
// Staging v3: wide float4/uint2 loads (16 lanes x 16B contiguous per row),
// in-lane pair pack, swizzled u32 LDS writes.
// K-loop: R1 form — unroll 2, loads inside loop, NO manual prefetch
// (full unroll + prefetch serialized loads under the 128-reg/16-wave cliff).
// ---------------------------------------------------------------------------
template<int SHIFT, int IN_BF16>
__global__ __launch_bounds__(512, 4) void hop_mfma(const void* __restrict__ xin_,
                                                   const u16* __restrict__ Atb,
                                                   u16* __restrict__ xout) {
    __shared__ u16 Xt[LL * VP];   // [l][v] swizzled, 64 KB
    const int nc = blockIdx.x;
    const int tid = threadIdx.x;
    const size_t base = (size_t)nc * (VV * LL);
    const int lane = tid & 63;
    const int wv = tid >> 6;

    // ---- stage (transpose + bf16, no shift) ----
    {
        char* ldsb = (char*)Xt;
        const int lquad = lane & 15;
        const int vsub = lane >> 4;     // 0..3
        const int l0 = 4 * lquad;
        #pragma unroll
        for (int i = 0; i < 8; ++i) {
            const int vp = wv * 32 + i * 4 + vsub;  // v-pair 0..255
            const int v0 = 2 * vp;
            u32 pk0, pk1, pk2, pk3;
            if (v0 < VV) {   // VV even => v0 < VV implies v0+1 < VV
                if (IN_BF16) {
                    const u16* xa = (const u16*)xin_ + base + v0 * LL + l0;
                    uint2 ua = *(const uint2*)xa;
                    uint2 ub = *(const uint2*)(xa + LL);
                    pk0 = (ua.x & 0xffffu) | (ub.x << 16);
                    pk1 = (ua.x >> 16) | (ub.x & 0xffff0000u);
                    pk2 = (ua.y & 0xffffu) | (ub.y << 16);
                    pk3 = (ua.y >> 16) | (ub.y & 0xffff0000u);
                } else {
                    const float* xa = (const float*)xin_ + base + v0 * LL + l0;
                    float4 fa = *(const float4*)xa;
                    float4 fb = *(const float4*)(xa + LL);
                    pk0 = (u32)f2bf(fa.x) | ((u32)f2bf(fb.x) << 16);
                    pk1 = (u32)f2bf(fa.y) | ((u32)f2bf(fb.y) << 16);
                    pk2 = (u32)f2bf(fa.z) | ((u32)f2bf(fb.z) << 16);
                    pk3 = (u32)f2bf(fa.w) | ((u32)f2bf(fb.w) << 16);
                }
            } else {
                pk0 = pk1 = pk2 = pk3 = 0;
            }
            const int vb = 4 * vp;
            int l = l0;
            *(u32*)(ldsb + l * (VP * 2) + (vb ^ ((l & 7) << 4))) = pk0; l++;
            *(u32*)(ldsb + l * (VP * 2) + (vb ^ ((l & 7) << 4))) = pk1; l++;
            *(u32*)(ldsb + l * (VP * 2) + (vb ^ ((l & 7) << 4))) = pk2; l++;
            *(u32*)(ldsb + l * (VP * 2) + (vb ^ ((l & 7) << 4))) = pk3;
        }
    }
    __syncthreads();

    // ---- MFMA main loop (R1 form: unroll 2, loads in-loop) ----
    const int wr = wv * 64;
    const int r15 = lane & 15;
    const int kg = lane >> 4;

    f32x4 acc[4][4];
    #pragma unroll
    for (int rt = 0; rt < 4; rt++)
        #pragma unroll
        for (int ct = 0; ct < 4; ct++)
            acc[rt][ct] = (f32x4){0.f, 0.f, 0.f, 0.f};

    const char* ldsb = (const char*)Xt;
    const u16* arow[4];
    #pragma unroll
    for (int rt = 0; rt < 4; rt++)
        arow[rt] = Atb + (size_t)(wr + rt * 16 + r15) * VP + kg * 8;
    int lrow[4], lswz[4];
    #pragma unroll
    for (int ct = 0; ct < 4; ct++) {
        const int l = ct * 16 + r15;
        lrow[ct] = l * (VP * 2);
        lswz[ct] = (l & 7) << 4;
    }

    #pragma unroll 2
    for (int kb = 0; kb < VP; kb += 32) {
        bf16x8 a[4], b[4];
        #pragma unroll
        for (int rt = 0; rt < 4; rt++)
            a[rt] = *(const bf16x8*)(arow[rt] + kb);
        #pragma unroll
        for (int ct = 0; ct < 4; ct++)
            b[ct] = *(const bf16x8*)(ldsb + lrow[ct] + ((kb * 2 + kg * 16) ^ lswz[ct]));
        #pragma unroll
        for (int rt = 0; rt < 4; rt++)
            #pragma unroll
            for (int ct = 0; ct < 4; ct++)
                acc[rt][ct] = __builtin_amdgcn_mfma_f32_16x16x32_bf16(a[rt], b[ct], acc[rt][ct], 0, 0, 0);
    }

    // ---- store with epilogue shift: out[w][col+SHIFT] = D[w][col] ----
    u16* xo = xout + base;
    #pragma unroll
    for (int rt = 0; rt < 4; rt++) {
        #pragma unroll
        for (int ct = 0; ct < 4; ct++) {
            const int col = ct * 16 + r15;
            const int wbase = wr + rt * 16 + kg * 4;
            f32x4 c = acc[rt][ct];
            #pragma unroll
            for (int r = 0; r < 4; r++) {
                int w = wbase + r;
                if (w < VV) {
                    if (SHIFT > 0 && col < SHIFT) xo[w * LL + col] = 0;
                    if (col + SHIFT < LL) xo[w * LL + col + SHIFT] = f2bf(c[r]);
                }
            }
        }
    }
}

// ---------------------------------------------------------------------------
// K3: MLP via MFMA (unchanged from R7 — near HBM floor).
// ---------------------------------------------------------------------------
__global__ __launch_bounds__(256, 3) void mlp_mfma(const float* __restrict__ x,
                                                   const u16* __restrict__ x1,
                                                   const u16* __restrict__ x2,
                                                   const u16* __restrict__ wb,
                                                   const float* __restrict__ b,
                                                   float* __restrict__ out) {
    __shared__ u16 Ht[128 * 192];   // 49152 B
    const int bid = blockIdx.x;
    const int n = bid / (SL / 128);
    const int st = bid - n * (SL / 128);
    const int s0 = st * 128;
    const int tid = threadIdx.x;

    const int lane = tid & 63;
    const int wv = tid >> 6;
    const int obase = (wv & 1) * 32;
    const int sbase = (wv >> 1) * 64;
    const int r15 = lane & 15;
    const int kg = lane >> 4;

    bf16x8 afrag[2][6];
    #pragma unroll
    for (int rt = 0; rt < 2; rt++)
        #pragma unroll
        for (int ks = 0; ks < 6; ks++)
            afrag[rt][ks] = *(const bf16x8*)(wb + (obase + rt * 16 + r15) * (3 * CC) + ks * 32 + kg * 8);

    // ---- staging: wide loads + swizzled writes ----
    {
        char* ldsb = (char*)Ht;
        const int squad = tid >> 3;      // 0..31
        const int pgroup = tid & 7;      // 0..7
        const int sq0 = 4 * squad;       // 0..124
        #pragma unroll
        for (int i = 0; i < 12; ++i) {
            const int P = i * 8 + pgroup;   // 0..95
            const int c = 2 * P;
            u32 pk0, pk1, pk2, pk3;
            if (i < 4) {    // c < 64: fp32 source
                const float* fsrc = x + ((size_t)n * CC + c) * SL + s0 + sq0;
                float4 va = *(const float4*)fsrc;
                float4 vb = *(const float4*)(fsrc + SL);
                pk0 = (u32)f2bf(va.x) | ((u32)f2bf(vb.x) << 16);
                pk1 = (u32)f2bf(va.y) | ((u32)f2bf(vb.y) << 16);
                pk2 = (u32)f2bf(va.z) | ((u32)f2bf(vb.z) << 16);
                pk3 = (u32)f2bf(va.w) | ((u32)f2bf(vb.w) << 16);
            } else {        // bf16 source (x1 for i<8, else x2)
                const u16* bsrc = (i < 8)
                    ? x1 + ((size_t)n * CC + (c - CC)) * SL + s0 + sq0
                    : x2 + ((size_t)n * CC + (c - 2 * CC)) * SL + s0 + sq0;
                uint2 va = *(const uint2*)bsrc;
                uint2 vb = *(const uint2*)(bsrc + SL);
                pk0 = (va.x & 0xffffu) | (vb.x << 16);
                pk1 = (va.x >> 16) | (vb.x & 0xffff0000u);
                pk2 = (va.y & 0xffffu) | (vb.y << 16);
                pk3 = (va.y >> 16) | (vb.y & 0xffff0000u);
            }
            int s = sq0;
            *(u32*)(ldsb + s * 384 + ((4 * P) ^ ((s & 7) << 4))) = pk0; s++;
            *(u32*)(ldsb + s * 384 + ((4 * P) ^ ((s & 7) << 4))) = pk1; s++;
            *(u32*)(ldsb + s * 384 + ((4 * P) ^ ((s & 7) << 4))) = pk2; s++;
            *(u32*)(ldsb + s * 384 + ((4 * P) ^ ((s & 7) << 4))) = pk3;
        }
    }
    __syncthreads();

    f32x4 acc[2][4];
    #pragma unroll
    for (int rt = 0; rt < 2; rt++)
        #pragma unroll
        for (int ct = 0; ct < 4; ct++)
            acc[rt][ct] = (f32x4){0.f, 0.f, 0.f, 0.f};

    const char* ldsb = (const char*)Ht;
    #pragma unroll
    for (int ks = 0; ks < 6; ks++) {
        bf16x8 bfr[4];
        #pragma unroll
        for (int ct = 0; ct < 4; ct++) {
            const int s = sbase + ct * 16 + r15;
            bfr[ct] = *(const bf16x8*)(ldsb + s * 384 + ((ks * 64 + kg * 16) ^ ((s & 7) << 4)));
        }
        #pragma unroll
        for (int rt = 0; rt < 2; rt++)
            #pragma unroll
            for (int ct = 0; ct < 4; ct++)
                acc[rt][ct] = __builtin_amdgcn_mfma_f32_16x16x32_bf16(afrag[rt][ks], bfr[ct], acc[rt][ct], 0, 0, 0);
    }

    #pragma unroll
    for (int rt = 0; rt < 2; rt++) {
        #pragma unroll
        for (int r = 0; r < 4; r++) {
            const int o = obase + rt * 16 + kg * 4 + r;
            const float bias = b[o];
            float* orow = out + ((size_t)n * CO + o) * SL + s0 + sbase;
            #pragma unroll
            for (int ct = 0; ct < 4; ct++)
                orow[ct * 16 + r15] = acc[rt][ct][r] + bias;
        }
    }
}

// ---------------------------------------------------------------------------
extern "C" void kernel_launch(void* const* d_in, const int* in_sizes, int n_in,
                              void* d_out, int out_size, void* d_ws, size_t ws_size,
                              hipStream_t stream) {
    const float* x     = (const float*)d_in[0];
    const float* nv1   = (const float*)d_in[1];
    const float* nv2   = (const float*)d_in[2];
    const float* et_w  = (const float*)d_in[3];
    const float* et_b  = (const float*)d_in[4];
    const float* mlp_w = (const float*)d_in[5];
    const float* mlp_b = (const float*)d_in[6];
    float* out = (float*)d_out;

    char* wsb = (char*)d_ws;
    size_t off = 0;
    auto alloc = [&](size_t bytes) {
        size_t o = off;
        off += (bytes + 255) & ~(size_t)255;
        return o;
    };
    u16*   Atb0 = (u16*)(wsb + alloc((size_t)VP * VP * 2));
    u16*   Atb1 = (u16*)(wsb + alloc((size_t)VP * VP * 2));
    float* nv1t = (float*)(wsb + alloc((size_t)VV * EE * 4));
    float* nv2t = (float*)(wsb + alloc((size_t)EE * VV * 4));
    u16*   wb   = (u16*)(wsb + alloc((size_t)CO * 3 * CC * 2));
    u16*   x1   = (u16*)(wsb + alloc((size_t)NB * CC * VV * LL * 2));
    u16*   x2   = (u16*)(wsb + alloc((size_t)NB * CC * VV * LL * 2));
    (void)in_sizes; (void)n_in; (void)out_size; (void)ws_size;

    const int embN = 2 * VV * EE + CO * 3 * CC;
    emb_kernel<<<(embN + 255) / 256, 256, 0, stream>>>(nv1, nv2, et_w, et_b, mlp_w, nv1t, nv2t, wb);
    adj_kernel<<<VP, 64, 0, stream>>>(nv1, nv2, Atb0);
    adj_kernel<<<VP, 64, 0, stream>>>(nv1t, nv2t, Atb1);
    hop_mfma<0, 0><<<NB * CC, 512, 0, stream>>>((const void*)x, Atb0, x1);
    hop_mfma<DIL, 1><<<NB * CC, 512, 0, stream>>>((const void*)x1, Atb1, x2);
    mlp_mfma<<<NB * (SL / 128), 256, 0, stream>>>(x, x1, x2, wb, mlp_b, out);
}